// Round 10
// baseline (70.772 us; speedup 1.0000x reference)
//
#include <hip/hip_runtime.h>
#include <math.h>

#define NW 11
#define NL 8
#define NPIX 1024

typedef float f2 __attribute__((ext_vector_type(2)));
typedef float f4 __attribute__((ext_vector_type(4)));

struct FTab { int C[NL][NW]; };   // C[l][b] = F_l(1<<b), composed CNOT ring

// Composed CNOT-ring permutation (validated rounds 1-9): ascending q,
// m ^= ((m>>pc)&1)<<pt, pc=10-q, pt=10-((q+r)%11).
static inline int fmap_h(int m, int r) {
    for (int q = 0; q < NW; ++q) {
        int pc = 10 - q;
        int qq = q + r; if (qq >= NW) qq -= NW;
        int pt = 10 - qq;
        m ^= ((m >> pc) & 1) << pt;
    }
    return m;
}

#define FMA2 __builtin_elementwise_fma

// ---- DPP lane-xor helpers (VALU pipe, no LDS) ----
template<int CTRL>
__device__ __forceinline__ float dpp_f(float x) {
    int xi = __float_as_int(x);
    int r  = __builtin_amdgcn_update_dpp(xi, xi, CTRL, 0xF, 0xF, false);
    return __int_as_float(r);
}
template<int CTRL>
__device__ __forceinline__ f2 dpp2(f2 v) {
    return (f2){dpp_f<CTRL>(v.x), dpp_f<CTRL>(v.y)};
}

// partner fetch for lane-bit butterflies (validated round 9)
// MODE 0: lane^8 (row_ror:8)  1: lane^4 (row_shl/shr:4 + sel)
// MODE 2: lane^2 (quad_perm)  3: lane^1 (quad_perm)
// AMD DPP convention: row_shr:N -> src[L-N], row_shl:N -> src[L+N].
template<int MODE>
__device__ __forceinline__ f2 bfetch(f2 v, int L) {
    if constexpr (MODE == 0) return dpp2<0x128>(v);       // row_ror:8 = lane^8
    else if constexpr (MODE == 1) {
        f2 fwd = dpp2<0x104>(v);   // row_shl:4 -> src[L+4]
        f2 bwd = dpp2<0x114>(v);   // row_shr:4 -> src[L-4]
        return (L & 4) ? bwd : fwd;
    }
    else if constexpr (MODE == 2) return dpp2<0x4E>(v);   // quad[2,3,0,1]
    else return dpp2<0xB1>(v);                            // quad[1,0,3,2]
}

// ---- reg<->lane bit swaps (VALU pipe) ----
// swap32: a@(L5=1) <-> b@(L5=0), pairing L <-> L^32 (validated round 9).
__device__ __forceinline__ void swap32(f2& a, f2& b) {
    float ax = a.x, ay = a.y, bx = b.x, by = b.y;
    asm volatile("v_permlane32_swap_b32 %0, %1" : "+v"(ax), "+v"(bx));
    asm volatile("v_permlane32_swap_b32 %0, %1" : "+v"(ay), "+v"(by));
    a = (f2){ax, ay}; b = (f2){bx, by};
}
// swap16: a@(L4=1) <-> b@(L4=0), pairing L <-> L^16 — odd 16-rows of vdst
// swap with even 16-rows of vsrc (exact analog of proven permlane32 form).
__device__ __forceinline__ void swap16(f2& a, f2& b) {
    float ax = a.x, ay = a.y, bx = b.x, by = b.y;
    asm volatile("v_permlane16_swap_b32 %0, %1" : "+v"(ax), "+v"(bx));
    asm volatile("v_permlane16_swap_b32 %0, %1" : "+v"(ay), "+v"(by));
    a = (f2){ax, ay}; b = (f2){bx, by};
}

// ---- gate on a register-resident bit (pairing mask M), packed complex ----
// g (global, wave-uniform -> s_load): {(u00r,u00r),(-u00i,u00i),(u01r,u01r),
// (-u01i,u01i),(u10r,u10r),(-u10i,u10i),(u11r,u11r),(-u11i,u11i)}
template<int M>
__device__ __forceinline__ void gateR(f2 (&X)[32], const f2* __restrict__ g) {
    const f2 c0 = g[0], c1 = g[1], c2 = g[2], c3 = g[3];
    const f2 c4 = g[4], c5 = g[5], c6 = g[6], c7 = g[7];
    #pragma unroll
    for (int s = 0; s < 32; ++s) {
        if (s & M) continue;
        const int s1 = s | M;
        f2 v0 = X[s], v1 = X[s1];
        f2 v0y = v0.yx, v1y = v1.yx;
        X[s]  = FMA2(c3, v1y, FMA2(c2, v1, FMA2(c1, v0y, c0 * v0)));
        X[s1] = FMA2(c7, v1y, FMA2(c6, v1, FMA2(c5, v0y, c4 * v0)));
    }
}

// ---- gate on a lane-resident bit via DPP butterfly exchange ----
template<int LBIT, int MODE>
__device__ __forceinline__ void gateL(f2 (&X)[32], const f2* __restrict__ g, int L) {
    const bool sb = (L >> LBIT) & 1;
    const f2 a0 = sb ? g[6] : g[0], a1 = sb ? g[7] : g[1];
    const f2 b0 = sb ? g[4] : g[2], b1 = sb ? g[5] : g[3];
    #pragma unroll
    for (int s = 0; s < 32; ++s) {
        f2 v = X[s];
        f2 p = bfetch<MODE>(v, L);
        f2 vy = v.yx, py = p.yx;
        X[s] = FMA2(b1, py, FMA2(b0, p, FMA2(a1, vy, a0 * v)));
    }
}

// ---- kernel 1: 88 Rot gate matrices -> d_ws (validated rounds 3/4) ----
__global__ void gates_kernel(const float* __restrict__ weights, f2* __restrict__ gw) {
    int t = threadIdx.x;
    if (t < NL * NW) {
        const float* w = weights + t * 3;
        const float PI = 3.14159265358979323846f;
        float phi   = PI * tanhf(w[0]);
        float theta = PI * tanhf(w[1]);
        float omega = PI * tanhf(w[2]);
        float ct = cosf(0.5f * theta), st = sinf(0.5f * theta);
        float a  = 0.5f * (phi + omega), bb = 0.5f * (phi - omega);
        float ca = cosf(a), sa = sinf(a), cb = cosf(bb), sb = sinf(bb);
        float u00r =  ca * ct, u00i = -sa * ct;
        float u01r = -cb * st, u01i = -sb * st;
        float u10r =  cb * st, u10i = -sb * st;
        float u11r =  ca * ct, u11i =  sa * ct;
        f2* g = gw + t * 8;
        g[0] = (f2){u00r, u00r}; g[1] = (f2){-u00i, u00i};
        g[2] = (f2){u01r, u01r}; g[3] = (f2){-u01i, u01i};
        g[4] = (f2){u10r, u10r}; g[5] = (f2){-u10i, u10i};
        g[6] = (f2){u11r, u11r}; g[7] = (f2){-u11i, u11i};
    }
}

// ---- kernel 2: one wave (64 threads) per batch element; state in 32 f2
// regs/lane. Canonical: reg bits j4..j0 = amp 10..6; lanes L5..L0 = amp 5..0.
// Zero __syncthreads; LDS only for psi staging + per-layer CNOT scatter.
// Coefs come from global gw via wave-uniform (scalar) loads.
__global__ __launch_bounds__(64) void pqc_kernel(
    const float* __restrict__ image, const float* __restrict__ label,
    const f2* __restrict__ gw, float* __restrict__ out, FTab ft)
{
    __shared__ __align__(16) f2 sS[2048];        // state scatter buffer (16 KB)

    const int b = blockIdx.x, L = threadIdx.x;

    // ---- image load + wave norm; stage raw psi in LDS ----
    float* psi = (float*)sS;
    const f4* img4 = (const f4*)(image + (size_t)b * NPIX);
    f4 xs[4];
    float ss = 0.f;
    #pragma unroll
    for (int k = 0; k < 4; ++k) {
        xs[k] = img4[L + 64 * k];
        ss += xs[k].x * xs[k].x + xs[k].y * xs[k].y
            + xs[k].z * xs[k].z + xs[k].w * xs[k].w;
    }
    #pragma unroll
    for (int o = 32; o >= 1; o >>= 1) ss += __shfl_xor(ss, o, 64);
    const float inv = 1.0f / sqrtf(ss);
    #pragma unroll
    for (int k = 0; k < 4; ++k) *(f4*)&psi[(L + 64 * k) * 4] = xs[k];
    asm volatile("s_waitcnt lgkmcnt(0)" ::: "memory");

    // ---- init + RX(label, wire10=amp bit0) folded; canonical layout ----
    const float lab = label[b];
    const float clp =  cosf(0.5f * lab) * inv;
    const float slp = -sinf(0.5f * lab) * inv;
    const bool odd = L & 1;
    f2 X[32];
    #pragma unroll
    for (int j = 0; j < 32; ++j) {
        float pv = psi[(j << 5) | (L >> 1)];
        X[j] = odd ? (f2){0.f, slp * pv} : (f2){clp * pv, 0.f};
    }
    asm volatile("s_waitcnt lgkmcnt(0)" ::: "memory");

    // ---- 8 layers ----
    for (int l = 0; l < NL; ++l) {
        const f2* G = gw + l * NW * 8;

        // wires 0..4 on reg bits (amp 10..6)
        gateR<16>(X, G + 0 * 8);
        gateR< 8>(X, G + 1 * 8);
        gateR< 4>(X, G + 2 * 8);
        gateR< 2>(X, G + 3 * 8);
        gateR< 1>(X, G + 4 * 8);

        // swap amp10(L5) <-> amp5(j4); then wire 5 on regs
        #pragma unroll
        for (int j = 0; j < 16; ++j) swap32(X[j], X[j + 16]);
        gateR<16>(X, G + 5 * 8);

        // swap amp9(L4) <-> amp4(j3); then wire 6 on regs
        #pragma unroll
        for (int jj = 0; jj < 16; ++jj) {
            int j = (jj & 7) | ((jj >> 3) << 4);
            swap16(X[j], X[j + 8]);
        }
        gateR<8>(X, G + 6 * 8);

        // wires 7..10 on lane bits 3..0 via DPP butterflies
        gateL<3, 0>(X, G + 7 * 8, L);   // amp3, lane^8
        gateL<2, 1>(X, G + 8 * 8, L);   // amp2, lane^4
        gateL<1, 2>(X, G + 9 * 8, L);   // amp1, lane^2
        gateL<0, 3>(X, G + 10 * 8, L);  // amp0, lane^1

        // ---- CNOT-ring permutation via LDS scatter (store e at F_l(e)) ----
        // layout here: regs j4..j0 = amp {5,4,8,7,6}; lanes L5..L0 = amp
        // {10,9,3,2,1,0}
        const int* C = ft.C[l];
        int FL = 0;
        FL ^= ((L >> 5) & 1) ? C[10] : 0;
        FL ^= ((L >> 4) & 1) ? C[9]  : 0;
        FL ^= ((L >> 3) & 1) ? C[3]  : 0;
        FL ^= ((L >> 2) & 1) ? C[2]  : 0;
        FL ^= ((L >> 1) & 1) ? C[1]  : 0;
        FL ^= ( L       & 1) ? C[0]  : 0;
        const int c5 = C[5], c4 = C[4], c8 = C[8], c7 = C[7], c6 = C[6];
        #pragma unroll
        for (int j = 0; j < 32; ++j) {
            int fr = ((j & 16) ? c5 : 0) ^ ((j & 8) ? c4 : 0)
                   ^ ((j & 4)  ? c8 : 0) ^ ((j & 2) ? c7 : 0)
                   ^ ((j & 1)  ? c6 : 0);
            sS[FL ^ fr] = X[j];
        }
        // RAW: gather must see all scatter writes (same wave).
        asm volatile("s_waitcnt lgkmcnt(0)" ::: "memory");
        __builtin_amdgcn_sched_barrier(0);
        // gather back canonical: X[j] = state[(j<<6)|L]; compiler inserts
        // partial lgkmcnt waits before gate uses (no full drain). WAR vs the
        // next layer's scatter is safe by dataflow (stores depend on gates,
        // gates depend on all gathered X).
        #pragma unroll
        for (int j = 0; j < 32; ++j) X[j] = sS[(j << 6) | L];
    }

    // ---- output: |amp[2p]|^2 * NPIX, p = (j<<5)|(L>>1) (even lanes) ----
    if (!odd) {
        float* ob = out + (size_t)b * NPIX + (L >> 1);
        #pragma unroll
        for (int j = 0; j < 32; ++j) {
            f2 a = X[j];
            ob[j << 5] = (a.x * a.x + a.y * a.y) * (float)NPIX;
        }
    }
}

extern "C" void kernel_launch(void* const* d_in, const int* in_sizes, int n_in,
                              void* d_out, int out_size, void* d_ws, size_t ws_size,
                              hipStream_t stream) {
    const float* image   = (const float*)d_in[0];
    const float* label   = (const float*)d_in[1];
    const float* weights = (const float*)d_in[2];
    float* out = (float*)d_out;
    f2* gw = (f2*)d_ws;   // 88 gates * 8 f2 = 5632 bytes

    FTab ft;
    for (int l = 0; l < NL; ++l)
        for (int bpos = 0; bpos < NW; ++bpos)
            ft.C[l][bpos] = fmap_h(1 << bpos, l + 1);   // r = l%(NW-1)+1 = l+1

    int batch = in_sizes[1];  // 1024
    gates_kernel<<<1, 128, 0, stream>>>(weights, gw);
    pqc_kernel<<<batch, 64, 0, stream>>>(image, label, gw, out, ft);
}

// Round 11
// 53.054 us; speedup vs baseline: 1.3340x; 1.3340x over previous
//
#include <hip/hip_runtime.h>
#include <math.h>

#define NW 11
#define NL 8
#define NPIX 1024
#define TPB 256

typedef float f2 __attribute__((ext_vector_type(2)));
typedef float f4 __attribute__((ext_vector_type(4)));

struct PermTab { int fe[NL][8]; int d[NL][8]; };

// Composed CNOT-ring permutation (validated rounds 1-10): ascending q,
// m ^= ((m>>pc)&1)<<pt, pc=10-q, pt=10-((q+r)%11).
static inline int fmap_h(int m, int r) {
    for (int q = 0; q < NW; ++q) {
        int pc = 10 - q;
        int qq = q + r; if (qq >= NW) qq -= NW;
        int pt = 10 - qq;
        m ^= ((m >> pc) & 1) << pt;
    }
    return m;
}

// GF(2)-linear LDS swizzle (f2 units): amp bits [6:4] XOR into [3:1].
// Hand-checked even bank spread for gather/store/passD-read/output phases.
__host__ __device__ constexpr int SW(int e) {
    return e ^ (((e >> 4) & 7) << 1);
}

#define FMA2 __builtin_elementwise_fma

// ---- DPP lane-xor helpers (VALU pipe; validated round 9) ----
template<int CTRL>
__device__ __forceinline__ float dpp_f(float x) {
    int xi = __float_as_int(x);
    int r  = __builtin_amdgcn_update_dpp(xi, xi, CTRL, 0xF, 0xF, false);
    return __int_as_float(r);
}
template<int CTRL>
__device__ __forceinline__ f2 dpp2(f2 v) {
    return (f2){dpp_f<CTRL>(v.x), dpp_f<CTRL>(v.y)};
}

// partner fetch: MODE 0: lane^8 (row_ror:8)  1: lane^4 (row_shl/shr:4+sel)
// 2: lane^2 (quad_perm)  3: lane^1 (quad_perm).
// DPP convention: row_shr:N -> src[L-N], row_shl:N -> src[L+N].
template<int MODE>
__device__ __forceinline__ f2 bfetch(f2 v, int L) {
    if constexpr (MODE == 0) return dpp2<0x128>(v);
    else if constexpr (MODE == 1) {
        f2 fwd = dpp2<0x104>(v);   // row_shl:4 -> src[L+4]
        f2 bwd = dpp2<0x114>(v);   // row_shr:4 -> src[L-4]
        return (L & 4) ? bwd : fwd;
    }
    else if constexpr (MODE == 2) return dpp2<0x4E>(v);   // quad[2,3,0,1]
    else return dpp2<0xB1>(v);                            // quad[1,0,3,2]
}

// ---- reg<->lane bit swaps (validated rounds 9/10; a = low-reg operand) ----
__device__ __forceinline__ void swap32(f2& a, f2& b) {
    float ax = a.x, ay = a.y, bx = b.x, by = b.y;
    asm volatile("v_permlane32_swap_b32 %0, %1" : "+v"(ax), "+v"(bx));
    asm volatile("v_permlane32_swap_b32 %0, %1" : "+v"(ay), "+v"(by));
    a = (f2){ax, ay}; b = (f2){bx, by};
}
__device__ __forceinline__ void swap16(f2& a, f2& b) {
    float ax = a.x, ay = a.y, bx = b.x, by = b.y;
    asm volatile("v_permlane16_swap_b32 %0, %1" : "+v"(ax), "+v"(bx));
    asm volatile("v_permlane16_swap_b32 %0, %1" : "+v"(ay), "+v"(by));
    a = (f2){ax, ay}; b = (f2){bx, by};
}

// ---- gate on a register-resident bit (pairing mask M) ----
template<int M>
__device__ __forceinline__ void gateR8(f2 (&X)[8], const f2* __restrict__ g) {
    const f2 c0 = g[0], c1 = g[1], c2 = g[2], c3 = g[3];
    const f2 c4 = g[4], c5 = g[5], c6 = g[6], c7 = g[7];
    #pragma unroll
    for (int s = 0; s < 8; ++s) {
        if (s & M) continue;
        const int s1 = s | M;
        f2 v0 = X[s], v1 = X[s1];
        f2 v0y = v0.yx, v1y = v1.yx;
        X[s]  = FMA2(c3, v1y, FMA2(c2, v1, FMA2(c1, v0y, c0 * v0)));
        X[s1] = FMA2(c7, v1y, FMA2(c6, v1, FMA2(c5, v0y, c4 * v0)));
    }
}

// ---- gate on a lane-resident bit via DPP butterfly (validated round 9) ----
template<int LBIT, int MODE>
__device__ __forceinline__ void gateL8(f2 (&X)[8], const f2* __restrict__ g, int L) {
    const bool sb = (L >> LBIT) & 1;
    const f2 a0 = sb ? g[6] : g[0], a1 = sb ? g[7] : g[1];
    const f2 b0 = sb ? g[4] : g[2], b1 = sb ? g[5] : g[3];
    #pragma unroll
    for (int s = 0; s < 8; ++s) {
        f2 v = X[s];
        f2 p = bfetch<MODE>(v, L);
        f2 vy = v.yx, py = p.yx;
        X[s] = FMA2(b1, py, FMA2(b0, p, FMA2(a1, vy, a0 * v)));
    }
}

// ---- kernel 1: 88 Rot gate matrices -> d_ws (validated rounds 3/4/10) ----
__global__ void gates_kernel(const float* __restrict__ weights, f2* __restrict__ gw) {
    int t = threadIdx.x;
    if (t < NL * NW) {
        const float* w = weights + t * 3;
        const float PI = 3.14159265358979323846f;
        float phi   = PI * tanhf(w[0]);
        float theta = PI * tanhf(w[1]);
        float omega = PI * tanhf(w[2]);
        float ct = cosf(0.5f * theta), st = sinf(0.5f * theta);
        float a  = 0.5f * (phi + omega), bb = 0.5f * (phi - omega);
        float ca = cosf(a), sa = sinf(a), cb = cosf(bb), sb = sinf(bb);
        float u00r =  ca * ct, u00i = -sa * ct;
        float u01r = -cb * st, u01i = -sb * st;
        float u10r =  cb * st, u10i = -sb * st;
        float u11r =  ca * ct, u11i =  sa * ct;
        f2* g = gw + t * 8;
        g[0] = (f2){u00r, u00r}; g[1] = (f2){-u00i, u00i};
        g[2] = (f2){u01r, u01r}; g[3] = (f2){-u01i, u01i};
        g[4] = (f2){u10r, u10r}; g[5] = (f2){-u10i, u10i};
        g[6] = (f2){u11r, u11r}; g[7] = (f2){-u11i, u11i};
    }
}

// ---- kernel 2: one 256-thread block (4 waves) per batch element.
// Per lane 8 f2. Canonical layout: regs j2..j0 = amp 2..0; lanes L5..L0 =
// amp 8..3; waves w1,w0 = amp 10,9. Per layer: 9 within-wave gates
// (regs + DPP + permlane swaps), then ONE LDS round trip: store->sA,
// barrier, read {amp0,9,10} cube, gates wires 1,0, CNOT-perm scatter->sB,
// barrier. Two buffers => no read/scatter race (round-6 lesson).
__global__ __launch_bounds__(TPB) void pqc_kernel(
    const float* __restrict__ image, const float* __restrict__ label,
    const f2* __restrict__ gw, float* __restrict__ out, PermTab pt)
{
    __shared__ __align__(16) f2 sA[2048];
    __shared__ __align__(16) f2 sB[2048];
    __shared__ float sRed[4];

    const int b = blockIdx.x, t = threadIdx.x;
    const int L = t & 63, w = t >> 6;

    // ---- image load + block norm (validated round 4) ----
    const f4 x = ((const f4*)(image + (size_t)b * NPIX))[t];
    float ss = x.x * x.x + x.y * x.y + x.z * x.z + x.w * x.w;
    #pragma unroll
    for (int off = 32; off >= 1; off >>= 1) ss += __shfl_down(ss, off);
    if ((t & 63) == 0) sRed[t >> 6] = ss;
    __syncthreads();
    const float inv = 1.0f / sqrtf(sRed[0] + sRed[1] + sRed[2] + sRed[3]);

    const float lab = label[b];
    const float cl = cosf(0.5f * lab), sl = sinf(0.5f * lab);

    // ---- init + RX(wire10 = amp bit0): amp e = j | L<<3 | w<<9;
    // even amp e -> psi[e>>1] = psi[4t + j>>1] ----
    f2 X[8];
    {
        float ps[4] = {x.x, x.y, x.z, x.w};
        #pragma unroll
        for (int m = 0; m < 4; ++m) {
            float p = ps[m] * inv;
            X[2 * m]     = (f2){cl * p, 0.f};
            X[2 * m + 1] = (f2){0.f, -sl * p};
        }
    }

    // ---- swizzled base addresses (f2 units) ----
    // gather (canonical): e0 = L<<3 | w<<9, offsets jh<<1 (amp bits 1,2)
    const int e0b  = (L << 3) | (w << 9);
    const int swb0 = e0b ^ (((e0b >> 4) & 7) << 1);
    // phase-1 store (post-gate layout: L5..L0 = amp 1,2,6,5,4,3; j2,j1 = amp 7,8)
    const int eb = ((L & 1) << 3) | (((L >> 1) & 1) << 4) | (((L >> 2) & 1) << 5)
                 | (((L >> 3) & 1) << 6) | (((L >> 4) & 1) << 2)
                 | (((L >> 5) & 1) << 1) | (w << 9);
    const int swb1 = eb ^ (((eb >> 4) & 7) << 1);
    // pass-D read: amp bits 1..8 <- t bits 0..7; k bits -> amp 9,10
    const int bD   = t << 1;
    const int swbD = bD ^ (((bD >> 4) & 7) << 1);

    for (int l = 0; l < NL; ++l) {
        const f2* G = gw + (size_t)l * NW * 8;

        // ---- gather canonical from sB (layers > 0) ----
        if (l) {
            #pragma unroll
            for (int jh = 0; jh < 4; ++jh) {
                f4 wv = *(const f4*)&sB[swb0 ^ (jh << 1)];
                X[2 * jh] = wv.xy; X[2 * jh + 1] = wv.zw;
            }
        }

        // ---- within-wave gates (no LDS, no barrier) ----
        gateR8<1>(X, G + 10 * 8);        // wire 10 = amp0 (j0)
        gateR8<2>(X, G +  9 * 8);        // wire  9 = amp1 (j1)
        gateR8<4>(X, G +  8 * 8);        // wire  8 = amp2 (j2)
        gateL8<0, 3>(X, G + 7 * 8, L);   // wire  7 = amp3 (L0, lane^1)
        gateL8<1, 2>(X, G + 6 * 8, L);   // wire  6 = amp4 (L1, lane^2)
        gateL8<2, 1>(X, G + 5 * 8, L);   // wire  5 = amp5 (L2, lane^4)
        gateL8<3, 0>(X, G + 4 * 8, L);   // wire  4 = amp6 (L3, lane^8)
        // wire 3 = amp7 (L4): swap j2<->L4, gate on regs
        swap16(X[0], X[4]); swap16(X[1], X[5]);
        swap16(X[2], X[6]); swap16(X[3], X[7]);
        gateR8<4>(X, G + 3 * 8);
        // wire 2 = amp8 (L5): swap j1<->L5, gate on regs
        swap32(X[0], X[2]); swap32(X[1], X[3]);
        swap32(X[4], X[6]); swap32(X[5], X[7]);
        gateR8<2>(X, G + 2 * 8);

        // ---- phase 1: store canonical -> sA (4 x b128) ----
        #pragma unroll
        for (int jh = 0; jh < 4; ++jh) {
            f4 wv; wv.xy = X[2 * jh]; wv.zw = X[2 * jh + 1];
            *(f4*)&sA[swb1 ^ ((jh & 1) << 8) ^ ((jh >> 1) << 7)] = wv;
        }
        __syncthreads();

        // ---- phase 2: read {amp0,9,10} cube, wires 1,0, perm scatter ----
        f2 Y[8];
        #pragma unroll
        for (int k = 0; k < 4; ++k) {
            f4 wv = *(const f4*)&sA[swbD ^ ((k & 1) << 9) ^ ((k >> 1) << 10)];
            Y[2 * k] = wv.xy; Y[2 * k + 1] = wv.zw;
        }
        gateR8<2>(Y, G + 1 * 8);   // wire 1 = amp9 (m1)
        gateR8<4>(Y, G + 0 * 8);   // wire 0 = amp10 (m2)
        int msw = 0;
        #pragma unroll
        for (int k2 = 0; k2 < 8; ++k2)
            msw ^= ((t >> k2) & 1) ? pt.fe[l][k2] : 0;
        #pragma unroll
        for (int s = 0; s < 8; ++s) sB[msw ^ pt.d[l][s]] = Y[s];
        __syncthreads();
    }

    // ---- output: |amp[2p]|^2 * NPIX, p = 4t + m ----
    {
        const int eo  = t << 3;
        const int swO = eo ^ (((eo >> 4) & 7) << 1);
        f4 o;
        #pragma unroll
        for (int m = 0; m < 4; ++m) {
            f4 wv = *(const f4*)&sB[swO ^ (m << 1)];
            ((float*)&o)[m] = (wv.x * wv.x + wv.y * wv.y) * (float)NPIX;
        }
        ((f4*)(out + (size_t)b * NPIX))[t] = o;
    }
}

extern "C" void kernel_launch(void* const* d_in, const int* in_sizes, int n_in,
                              void* d_out, int out_size, void* d_ws, size_t ws_size,
                              hipStream_t stream) {
    const float* image   = (const float*)d_in[0];
    const float* label   = (const float*)d_in[1];
    const float* weights = (const float*)d_in[2];
    float* out = (float*)d_out;
    f2* gw = (f2*)d_ws;   // 88 gates * 8 f2 = 5632 bytes

    // host permutation tables (round-4 structure, new SW)
    PermTab pt;
    for (int l = 0; l < NL; ++l) {
        int r = l + 1;
        for (int k = 0; k < 8; ++k)
            pt.fe[l][k] = SW(fmap_h(1 << (k + 1), r));   // t bit k -> amp bit k+1
        for (int s = 0; s < 8; ++s) {
            int m = 0;
            if (s & 1) m ^= fmap_h(1,       r);          // s bit0 -> amp 0
            if (s & 2) m ^= fmap_h(1 << 9,  r);          // s bit1 -> amp 9
            if (s & 4) m ^= fmap_h(1 << 10, r);          // s bit2 -> amp 10
            pt.d[l][s] = SW(m);
        }
    }

    int batch = in_sizes[1];  // 1024
    gates_kernel<<<1, 128, 0, stream>>>(weights, gw);
    pqc_kernel<<<batch, TPB, 0, stream>>>(image, label, gw, out, pt);
}